// Round 8
// baseline (591.824 us; speedup 1.0000x reference)
//
#include <hip/hip_runtime.h>
#include <hip/hip_bf16.h>
#include <math.h>

#define Bq 64
#define Tq 2048
#define Eq 256
#define Dq 256
#define Iq 256

using short8  = __attribute__((ext_vector_type(8))) short;
using floatx4 = __attribute__((ext_vector_type(4))) float;

// tanh via fast exp + v_rcp approx (error ~1e-6, bf16 GEMM noise dominates)
__device__ __forceinline__ float fast_tanh(float x) {
    float e = __expf(2.0f * x);
    return fmaf(-2.0f, __builtin_amdgcn_rcpf(e + 1.0f), 1.0f);
}

__device__ __forceinline__ ushort f2bf(float x) {
    union { __hip_bfloat16 h; ushort u; } c;
    c.h = __float2bfloat16(x);
    return c.u;
}

// async 16B/lane global -> LDS (dest = wave-uniform base + lane*16)
__device__ __forceinline__ void async_load16(const void* g, void* l) {
    __builtin_amdgcn_global_load_lds(
        (const __attribute__((address_space(1))) void*)g,
        (__attribute__((address_space(3))) void*)l, 16, 0, 0);
}

// stage one 64t x 256e fp32 row-contiguous tile, XOR-source-swizzled:
// LDS[r][slot s] = enc[r][chunk s ^ (r&15)]
__device__ __forceinline__ void stage_tile(const float* encB, float* Af,
                                           int w, int l) {
    #pragma unroll
    for (int q = 0; q < 16; ++q) {
        const int r = w * 16 + q;
        async_load16(encB + (size_t)r * Eq + (l ^ (r & 15)) * 4, &Af[r * 256]);
    }
}

// Fused prep:
//  blocks 0..31 : w1 fp32 -> bf16 fragment-ordered: w1sw[kc][i][8], kc=k/8
//  blocks 32..95: dec_proj[b][i] = sum_d dec[b][d]*w2[i][d], b=blockIdx-32
__global__ __launch_bounds__(256) void prep_kernel(
    const float* __restrict__ w1, ushort* __restrict__ w1sw,
    const float* __restrict__ dec, const float* __restrict__ w2,
    float* __restrict__ dproj)
{
    if (blockIdx.x < 32) {
        const int kc = blockIdx.x;
        const int i  = threadIdx.x;
        const float* src = w1 + i * Eq + kc * 8;
        float4 f0 = *(const float4*)src;
        float4 f1 = *(const float4*)(src + 4);
        ushort u[8] = { f2bf(f0.x), f2bf(f0.y), f2bf(f0.z), f2bf(f0.w),
                        f2bf(f1.x), f2bf(f1.y), f2bf(f1.z), f2bf(f1.w) };
        *(short8*)&w1sw[(kc * 256 + i) * 8] = *(short8*)u;
    } else {
        const int b = blockIdx.x - 32;
        const int i = threadIdx.x;
        __shared__ float dls[Dq];
        dls[i] = dec[b * Dq + i];
        __syncthreads();
        const float* w2r = w2 + i * Dq;
        float acc = 0.f;
        #pragma unroll 8
        for (int d = 0; d < Dq; d += 4) {
            float4 wv = *(const float4*)&w2r[d];
            float4 dv = *(const float4*)&dls[d];
            acc += wv.x * dv.x + wv.y * dv.y + wv.z * dv.z + wv.w * dv.w;
        }
        dproj[b * Iq + i] = acc;
    }
}

// ---- DIAG 1: staging x6 distinct tiles (768 MB > L3 -> sustained read) ----
__global__ __launch_bounds__(256, 2) void diag_stage_kernel(
    const float* __restrict__ enc, float* __restrict__ diag)
{
    const int b   = blockIdx.y;
    const int tid = threadIdx.x;
    const int w   = tid >> 6;
    const int l   = tid & 63;
    __shared__ alignas(16) float Af[64 * 256];
    float chk = 0.f;
    #pragma unroll 1
    for (int q = 0; q < 6; ++q) {
        const int bxq = (int)((blockIdx.x + 5u * q) & 31u);  // 6 distinct tiles
        const float* encB = enc + ((size_t)b * Tq + bxq * 64) * Eq;
        stage_tile(encB, Af, w, l);
        __syncthreads();          // drain
        chk += Af[tid * 64];
        __syncthreads();          // protect before overwrite
    }
    const int bid = blockIdx.y * gridDim.x + blockIdx.x;
    diag[(size_t)bid * 256 + tid] = chk;
}

// ---- DIAG 2: stage once + GEMM phase x10 (acc carried; loads re-executed) ----
__global__ __launch_bounds__(256, 2) void diag_gemm_kernel(
    const float* __restrict__ enc, const ushort* __restrict__ w1sw,
    float* __restrict__ diag)
{
    const int b   = blockIdx.y;
    const int t0  = blockIdx.x * 64;
    const int tid = threadIdx.x;
    const int w   = tid >> 6;
    const int l   = tid & 63;
    const int l15 = l & 15;
    const int lq  = l >> 4;

    __shared__ alignas(16) float Af[64 * 256];
    const float* encB = enc + ((size_t)b * Tq + t0) * Eq;
    stage_tile(encB, Af, w, l);

    floatx4 acc[4][4];
    #pragma unroll
    for (int mi = 0; mi < 4; ++mi)
        #pragma unroll
        for (int ni = 0; ni < 4; ++ni)
            acc[mi][ni] = (floatx4)0.f;

    __syncthreads();

    const ushort* vb = w1sw + (w * 64 + l15) * 8 + lq * 2048;
    #pragma unroll 1
    for (int rep = 0; rep < 10; ++rep) {
        asm volatile("" ::: "memory");   // force re-load of Af/bfv each rep
        #pragma unroll
        for (int kk = 0; kk < 8; ++kk) {
            short8 bfv[4];
            #pragma unroll
            for (int ni = 0; ni < 4; ++ni)
                bfv[ni] = *(const short8*)(vb + kk * 4 * 2048 + ni * 128);
            short8 af[4];
            #pragma unroll
            for (int mi = 0; mi < 4; ++mi) {
                const int r  = mi * 16 + l15;
                const int c0 = kk * 8 + lq * 2;
                const int s0 = c0 ^ l15;
                float4 f0 = *(const float4*)&Af[r * 256 + s0 * 4];
                float4 f1 = *(const float4*)&Af[r * 256 + (s0 ^ 1) * 4];
                ushort u[8] = { f2bf(f0.x), f2bf(f0.y), f2bf(f0.z), f2bf(f0.w),
                                f2bf(f1.x), f2bf(f1.y), f2bf(f1.z), f2bf(f1.w) };
                af[mi] = *(short8*)u;
            }
            __builtin_amdgcn_s_setprio(1);
            #pragma unroll
            for (int mi = 0; mi < 4; ++mi)
                #pragma unroll
                for (int ni = 0; ni < 4; ++ni)
                    acc[mi][ni] = __builtin_amdgcn_mfma_f32_16x16x32_bf16(
                        af[mi], bfv[ni], acc[mi][ni], 0, 0, 0);
            __builtin_amdgcn_s_setprio(0);
        }
    }

    float s = 0.f;
    #pragma unroll
    for (int mi = 0; mi < 4; ++mi)
        #pragma unroll
        for (int ni = 0; ni < 4; ++ni)
            #pragma unroll
            for (int r = 0; r < 4; ++r) s += acc[mi][ni][r];
    const int bid = blockIdx.y * gridDim.x + blockIdx.x;
    diag[(size_t)bid * 256 + tid] = s;
}

// ---- DIAG 3: stage once + epilogue x10 (fake acc from LDS: 64 DISTINCT
//      tanh inputs per thread -> no CSE; writes re-done each rep) ----
__global__ __launch_bounds__(256, 2) void diag_epi_kernel(
    const float* __restrict__ enc, const float* __restrict__ v,
    const float* __restrict__ dproj, float* __restrict__ escore,
    float* __restrict__ ctxp, float* __restrict__ denomp)
{
    const int b   = blockIdx.y;
    const int bx  = blockIdx.x;
    const int t0  = bx * 64;
    const int tid = threadIdx.x;
    const int w   = tid >> 6;
    const int l   = tid & 63;
    const int l15 = l & 15;
    const int lq  = l >> 4;

    __shared__ alignas(16) float Af[64 * 256];
    __shared__ float swred[4 * 64];
    __shared__ float redf[4 * 256];

    const float* encB = enc + ((size_t)b * Tq + t0) * Eq;
    stage_tile(encB, Af, w, l);

    float vv[4], dd[4];
    #pragma unroll
    for (int ni = 0; ni < 4; ++ni) {
        const int i = w * 64 + ni * 16 + l15;
        vv[ni] = v[i];
        dd[ni] = dproj[b * Iq + i];
    }
    __syncthreads();

    // fake accumulator: 64 distinct small values per thread (realistic tanh args)
    floatx4 facc[4][4];
    #pragma unroll
    for (int mi = 0; mi < 4; ++mi)
        #pragma unroll
        for (int ni = 0; ni < 4; ++ni)
            #pragma unroll
            for (int r = 0; r < 4; ++r)
                facc[mi][ni][r] = Af[(mi * 16 + l15) * 256 + ((ni * 4 + r) * 4 + lq)];

    #pragma unroll 1
    for (int rep = 0; rep < 10; ++rep) {
        asm volatile("" ::: "memory");
        float part[4][4];
        #pragma unroll
        for (int mi = 0; mi < 4; ++mi)
            #pragma unroll
            for (int r = 0; r < 4; ++r) part[mi][r] = 0.f;
        #pragma unroll
        for (int ni = 0; ni < 4; ++ni) {
            const float vi = vv[ni];
            const float dp = dd[ni];
            #pragma unroll
            for (int mi = 0; mi < 4; ++mi)
                #pragma unroll
                for (int r = 0; r < 4; ++r)
                    part[mi][r] += vi * fast_tanh(facc[mi][ni][r] + dp);
        }
        #pragma unroll
        for (int mi = 0; mi < 4; ++mi)
            #pragma unroll
            for (int r = 0; r < 4; ++r) {
                float x = part[mi][r];
                x += __shfl_xor(x, 1); x += __shfl_xor(x, 2);
                x += __shfl_xor(x, 4); x += __shfl_xor(x, 8);
                part[mi][r] = x;
            }
        if (l15 == 0) {
            #pragma unroll
            for (int mi = 0; mi < 4; ++mi)
                #pragma unroll
                for (int r = 0; r < 4; ++r)
                    swred[w * 64 + mi * 16 + lq * 4 + r] = part[mi][r];
        }
        __syncthreads();

        float s = swred[l] + swred[64 + l] + swred[128 + l] + swred[192 + l];
        const float es = __expf(s * 1e-6f);   // keep finite (fake acc scale)
        if (w == 0) {
            escore[(size_t)b * Tq + t0 + l] = es;
            float tot = es;
            tot += __shfl_xor(tot, 1);  tot += __shfl_xor(tot, 2);
            tot += __shfl_xor(tot, 4);  tot += __shfl_xor(tot, 8);
            tot += __shfl_xor(tot, 16); tot += __shfl_xor(tot, 32);
            if (l == 0) denomp[bx * Bq + b] = tot;
        }

        const int el = l * 4;
        float4 a = {0.f, 0.f, 0.f, 0.f};
        #pragma unroll 8
        for (int tt = 0; tt < 16; ++tt) {
            const int t  = w * 16 + tt;
            const float pt = __shfl(es, t);
            const int sl = l ^ (t & 15);
            float4 ev = *(const float4*)&Af[t * 256 + sl * 4];
            a.x += pt * ev.x; a.y += pt * ev.y; a.z += pt * ev.z; a.w += pt * ev.w;
        }
        *(float4*)&redf[w * 256 + el] = a;
        __syncthreads();
        if (w == 0) {
            float4 a0 = *(const float4*)&redf[0 * 256 + el];
            float4 a1 = *(const float4*)&redf[1 * 256 + el];
            float4 a2 = *(const float4*)&redf[2 * 256 + el];
            float4 a3 = *(const float4*)&redf[3 * 256 + el];
            float4 o;
            o.x = a0.x + a1.x + a2.x + a3.x;
            o.y = a0.y + a1.y + a2.y + a3.y;
            o.z = a0.z + a1.z + a2.z + a3.z;
            o.w = a0.w + a1.w + a2.w + a3.w;
            *(float4*)&ctxp[((size_t)bx * Bq + b) * Eq + el] = o;
        }
        __syncthreads();
    }
}

// ---------- REAL kernel: unchanged R6 (whole-tile staging) ----------
__global__ __launch_bounds__(256, 2) void scores_ctx_kernel(
    const float*  __restrict__ enc,
    const ushort* __restrict__ w1sw,
    const float*  __restrict__ v,
    const float*  __restrict__ dproj,
    float* __restrict__ escore,
    float* __restrict__ ctxp,
    float* __restrict__ denomp)
{
    const int b   = blockIdx.y;
    const int bx  = blockIdx.x;
    const int t0  = bx * 64;
    const int tid = threadIdx.x;
    const int w   = tid >> 6;
    const int l   = tid & 63;
    const int l15 = l & 15;
    const int lq  = l >> 4;

    __shared__ alignas(16) float Af[64 * 256];
    __shared__ float swred[4 * 64];
    __shared__ float redf[4 * 256];

    const float* encB = enc + ((size_t)b * Tq + t0) * Eq;
    stage_tile(encB, Af, w, l);

    float vv[4], dd[4];
    #pragma unroll
    for (int ni = 0; ni < 4; ++ni) {
        const int i = w * 64 + ni * 16 + l15;
        vv[ni] = v[i];
        dd[ni] = dproj[b * Iq + i];
    }

    floatx4 acc[4][4];
    #pragma unroll
    for (int mi = 0; mi < 4; ++mi)
        #pragma unroll
        for (int ni = 0; ni < 4; ++ni)
            acc[mi][ni] = (floatx4)0.f;

    __syncthreads();

    const ushort* vb = w1sw + (w * 64 + l15) * 8 + lq * 2048;
    #pragma unroll
    for (int kk = 0; kk < 8; ++kk) {
        short8 bfv[4];
        #pragma unroll
        for (int ni = 0; ni < 4; ++ni)
            bfv[ni] = *(const short8*)(vb + kk * 4 * 2048 + ni * 128);
        short8 af[4];
        #pragma unroll
        for (int mi = 0; mi < 4; ++mi) {
            const int r  = mi * 16 + l15;
            const int c0 = kk * 8 + lq * 2;
            const int s0 = c0 ^ l15;
            float4 f0 = *(const float4*)&Af[r * 256 + s0 * 4];
            float4 f1 = *(const float4*)&Af[r * 256 + (s0 ^ 1) * 4];
            ushort u[8] = { f2bf(f0.x), f2bf(f0.y), f2bf(f0.z), f2bf(f0.w),
                            f2bf(f1.x), f2bf(f1.y), f2bf(f1.z), f2bf(f1.w) };
            af[mi] = *(short8*)u;
        }
        __builtin_amdgcn_s_setprio(1);
        #pragma unroll
        for (int mi = 0; mi < 4; ++mi)
            #pragma unroll
            for (int ni = 0; ni < 4; ++ni)
                acc[mi][ni] = __builtin_amdgcn_mfma_f32_16x16x32_bf16(
                    af[mi], bfv[ni], acc[mi][ni], 0, 0, 0);
        __builtin_amdgcn_s_setprio(0);
    }

    float part[4][4];
    #pragma unroll
    for (int mi = 0; mi < 4; ++mi)
        #pragma unroll
        for (int r = 0; r < 4; ++r) part[mi][r] = 0.f;
    #pragma unroll
    for (int ni = 0; ni < 4; ++ni) {
        const float vi = vv[ni];
        const float dp = dd[ni];
        #pragma unroll
        for (int mi = 0; mi < 4; ++mi)
            #pragma unroll
            for (int r = 0; r < 4; ++r)
                part[mi][r] += vi * fast_tanh(acc[mi][ni][r] + dp);
    }
    #pragma unroll
    for (int mi = 0; mi < 4; ++mi)
        #pragma unroll
        for (int r = 0; r < 4; ++r) {
            float x = part[mi][r];
            x += __shfl_xor(x, 1); x += __shfl_xor(x, 2);
            x += __shfl_xor(x, 4); x += __shfl_xor(x, 8);
            part[mi][r] = x;
        }
    if (l15 == 0) {
        #pragma unroll
        for (int mi = 0; mi < 4; ++mi)
            #pragma unroll
            for (int r = 0; r < 4; ++r)
                swred[w * 64 + mi * 16 + lq * 4 + r] = part[mi][r];
    }
    __syncthreads();

    float s = swred[l] + swred[64 + l] + swred[128 + l] + swred[192 + l];
    const float es = __expf(s);
    if (w == 0) {
        escore[(size_t)b * Tq + t0 + l] = es;
        float tot = es;
        tot += __shfl_xor(tot, 1);  tot += __shfl_xor(tot, 2);
        tot += __shfl_xor(tot, 4);  tot += __shfl_xor(tot, 8);
        tot += __shfl_xor(tot, 16); tot += __shfl_xor(tot, 32);
        if (l == 0) denomp[bx * Bq + b] = tot;
    }

    const int el = l * 4;
    float4 a = {0.f, 0.f, 0.f, 0.f};
    #pragma unroll 8
    for (int tt = 0; tt < 16; ++tt) {
        const int t  = w * 16 + tt;
        const float pt = __shfl(es, t);
        const int sl = l ^ (t & 15);
        float4 ev = *(const float4*)&Af[t * 256 + sl * 4];
        a.x += pt * ev.x; a.y += pt * ev.y; a.z += pt * ev.z; a.w += pt * ev.w;
    }
    *(float4*)&redf[w * 256 + el] = a;
    __syncthreads();
    if (w == 0) {
        float4 a0 = *(const float4*)&redf[0 * 256 + el];
        float4 a1 = *(const float4*)&redf[1 * 256 + el];
        float4 a2 = *(const float4*)&redf[2 * 256 + el];
        float4 a3 = *(const float4*)&redf[3 * 256 + el];
        float4 o;
        o.x = a0.x + a1.x + a2.x + a3.x;
        o.y = a0.y + a1.y + a2.y + a3.y;
        o.z = a0.z + a1.z + a2.z + a3.z;
        o.w = a0.w + a1.w + a2.w + a3.w;
        *(float4*)&ctxp[((size_t)bx * Bq + b) * Eq + el] = o;
    }
}

// One block per b: denom = sum_c denomp[c][b]; probs *= 1/denom (in place);
// ctx[b][e] = (sum_c ctxp[c][b][e]) / denom.
__global__ __launch_bounds__(256) void finalize_kernel(
    const float* __restrict__ ctxp, const float* __restrict__ denomp,
    float* __restrict__ probs, float* __restrict__ ctx)
{
    const int b   = blockIdx.x;
    const int tid = threadIdx.x;

    float d = denomp[(tid & 31) * Bq + b];
    d += __shfl_xor(d, 1);  d += __shfl_xor(d, 2);  d += __shfl_xor(d, 4);
    d += __shfl_xor(d, 8);  d += __shfl_xor(d, 16);
    const float inv = 1.0f / d;

    float* prow = probs + (size_t)b * Tq + tid * 8;
    float4 p0 = *(const float4*)(prow + 0);
    float4 p1 = *(const float4*)(prow + 4);
    p0.x *= inv; p0.y *= inv; p0.z *= inv; p0.w *= inv;
    p1.x *= inv; p1.y *= inv; p1.z *= inv; p1.w *= inv;
    *(float4*)(prow + 0) = p0;
    *(float4*)(prow + 4) = p1;

    float s = 0.f;
    #pragma unroll 8
    for (int c = 0; c < 32; ++c)
        s += ctxp[((size_t)c * Bq + b) * Eq + tid];
    ctx[b * Eq + tid] = s * inv;
}

extern "C" void kernel_launch(void* const* d_in, const int* in_sizes, int n_in,
                              void* d_out, int out_size, void* d_ws, size_t ws_size,
                              hipStream_t stream) {
    const float* enc = (const float*)d_in[0];
    const float* dec = (const float*)d_in[1];
    const float* w1  = (const float*)d_in[2];
    const float* w2  = (const float*)d_in[3];
    const float* v   = (const float*)d_in[4];

    float* out   = (float*)d_out;
    float* ctx   = out;                 // [64][256]  output 0
    float* probs = out + Bq * Eq;       // [64][2048] output 1 (escore first)

    char* ws = (char*)d_ws;
    float*  ctxp   = (float*)ws;                                       // 2 MB
    float*  denomp = (float*)(ws + 2097152);                           // 8 KB
    float*  dproj  = (float*)(ws + 2097152 + 8192);                    // 64 KB
    ushort* w1sw   = (ushort*)(ws + 2097152 + 8192 + 65536);           // 128 KB
    float*  diag   = (float*)(ws + 2097152 + 8192 + 65536 + 131072);   // 2 MB

    prep_kernel<<<dim3(96), dim3(256), 0, stream>>>(w1, w1sw, dec, w2, dproj);

    // ---- amplified diagnostics (scratch / fully-overwritten buffers only)
    diag_stage_kernel<<<dim3(Tq / 64, Bq), dim3(256), 0, stream>>>(enc, diag);
    diag_gemm_kernel<<<dim3(Tq / 64, Bq), dim3(256), 0, stream>>>(enc, w1sw, diag);
    diag_epi_kernel<<<dim3(Tq / 64, Bq), dim3(256), 0, stream>>>(
        enc, v, dproj, probs, ctxp, denomp);

    // ---- real pipeline (unchanged R6)
    scores_ctx_kernel<<<dim3(Tq / 64, Bq), dim3(256), 0, stream>>>(
        enc, w1sw, v, dproj, probs, ctxp, denomp);
    finalize_kernel<<<dim3(Bq), dim3(256), 0, stream>>>(ctxp, denomp, probs, ctx);
}

// Round 9
// 231.876 us; speedup vs baseline: 2.5523x; 2.5523x over previous
//
#include <hip/hip_runtime.h>
#include <hip/hip_bf16.h>
#include <math.h>

#define Bq 64
#define Tq 2048
#define Eq 256
#define Dq 256
#define Iq 256

using short8  = __attribute__((ext_vector_type(8))) short;
using floatx4 = __attribute__((ext_vector_type(4))) float;

// tanh via fast exp + v_rcp approx (error ~1e-6, bf16 GEMM noise dominates)
__device__ __forceinline__ float fast_tanh(float x) {
    float e = __expf(2.0f * x);
    return fmaf(-2.0f, __builtin_amdgcn_rcpf(e + 1.0f), 1.0f);
}

__device__ __forceinline__ ushort f2bf(float x) {
    union { __hip_bfloat16 h; ushort u; } c;
    c.h = __float2bfloat16(x);
    return c.u;
}

// async 16B/lane global -> LDS (dest = wave-uniform base + lane*16)
__device__ __forceinline__ void async_load16(const void* g, void* l) {
    __builtin_amdgcn_global_load_lds(
        (const __attribute__((address_space(1))) void*)g,
        (__attribute__((address_space(3))) void*)l, 16, 0, 0);
}

// Fused prep:
//  blocks 0..31 : w1 fp32 -> bf16 fragment-ordered: w1sw[kc][i][8], kc=k/8
//  blocks 32..95: dec_proj[b][i] = sum_d dec[b][d]*w2[i][d], b=blockIdx-32
__global__ __launch_bounds__(256) void prep_kernel(
    const float* __restrict__ w1, ushort* __restrict__ w1sw,
    const float* __restrict__ dec, const float* __restrict__ w2,
    float* __restrict__ dproj)
{
    if (blockIdx.x < 32) {
        const int kc = blockIdx.x;
        const int i  = threadIdx.x;
        const float* src = w1 + i * Eq + kc * 8;
        float4 f0 = *(const float4*)src;
        float4 f1 = *(const float4*)(src + 4);
        ushort u[8] = { f2bf(f0.x), f2bf(f0.y), f2bf(f0.z), f2bf(f0.w),
                        f2bf(f1.x), f2bf(f1.y), f2bf(f1.z), f2bf(f1.w) };
        *(short8*)&w1sw[(kc * 256 + i) * 8] = *(short8*)u;
    } else {
        const int b = blockIdx.x - 32;
        const int i = threadIdx.x;
        __shared__ float dls[Dq];
        dls[i] = dec[b * Dq + i];
        __syncthreads();
        const float* w2r = w2 + i * Dq;
        float acc = 0.f;
        #pragma unroll 8
        for (int d = 0; d < Dq; d += 4) {
            float4 wv = *(const float4*)&w2r[d];
            float4 dv = *(const float4*)&dls[d];
            acc += wv.x * dv.x + wv.y * dv.y + wv.z * dv.z + wv.w * dv.w;
        }
        dproj[b * Iq + i] = acc;
    }
}

// Fused scores + unnormalized-context, v7: PERSISTENT blocks.
//  R8 ablation: GEMM phase 12.4us @60% MfmaUtil (near floor), epi ~7us,
//  DMA path sustains ~6TB/s when back-to-back (diag_stage) -- but the real
//  kernel ran at 1.4TB/s: demand-limited (short blocks issue 64KB, drain,
//  compute 2.4us issuing nothing, exit). Fix: 1 block/CU (256 x 512thr,
//  8 waves), each owns 8 consecutive tiles; depth-2 whole-tile pipeline:
//   tile j: issue STAGE(j+1 -> buf^1) -> vmcnt(8) [retires stage(j)+stores,
//   leaves stage(j+1) IN FLIGHT] -> raw s_barrier -> GEMM(buf) -> epilogue
//   with lgkmcnt-only raw barriers (NO __syncthreads => no vmcnt(0) drain).
//  B-panel preloaded ONCE into 64 VGPR/lane (i-split 8x32): zero VMEM in
//  the GEMM loop -> exact vmcnt accounting + no redundant B re-reads.
__global__ __launch_bounds__(512, 2) void scores_ctx_kernel(
    const float*  __restrict__ enc,    // [B][T][E] fp32
    const ushort* __restrict__ w1sw,   // fragment-ordered bf16 [32 kc][256 i][8]
    const float*  __restrict__ v,      // [I]
    const float*  __restrict__ dproj,  // [B][I]
    float* __restrict__ escore,        // [B][T] unnormalized exp (probs buffer)
    float* __restrict__ ctxp,          // [32][B][E] context partials
    float* __restrict__ denomp)        // [32][B]
{
    const int p   = blockIdx.x;        // 0..255, persistent
    const int b   = p >> 2;            // batch row (constant per block)
    const int bx0 = (p & 3) * 8;       // first of 8 consecutive tiles
    const int tid = threadIdx.x;
    const int w   = tid >> 6;          // wave 0..7
    const int l   = tid & 63;
    const int l15 = l & 15;
    const int lq  = l >> 4;

    __shared__ alignas(16) float Af[2][64 * 256];  // 128 KB double buffer
    __shared__ float swred[8 * 64];                // 2 KB
    __shared__ float redf[8 * 256];                // 8 KB

    // ---- preload B panel: wave w covers i in [w*32, w*32+32); 64 VGPR ----
    const ushort* vb = w1sw + (w * 32 + l15) * 8 + lq * 2048;
    short8 bP[8][2];
    #pragma unroll
    for (int kk = 0; kk < 8; ++kk)
        #pragma unroll
        for (int ni = 0; ni < 2; ++ni)
            bP[kk][ni] = *(const short8*)(vb + kk * 8192 + ni * 128);

    float vv[2], dd[2];
    #pragma unroll
    for (int ni = 0; ni < 2; ++ni) {
        const int i = w * 32 + ni * 16 + l15;
        vv[ni] = v[i];
        dd[ni] = dproj[b * Iq + i];
    }
    // retire all scalar-path loads so DMA vmcnt accounting is exact
    asm volatile("s_waitcnt vmcnt(0)" ::: "memory");
    __builtin_amdgcn_sched_barrier(0);

    // STAGE one 64x256 fp32 tile (row-contiguous DMA, XOR source swizzle):
    //  wave w stages rows w*8..w*8+7; LDS[r][s] = enc[r][chunk s ^ (r&15)]
    #define STAGE(bxx, buf)                                                  \
        _Pragma("unroll")                                                    \
        for (int q = 0; q < 8; ++q) {                                        \
            const int r = w * 8 + q;                                         \
            async_load16(enc + ((size_t)b * Tq + (bxx) * 64 + r) * Eq        \
                             + (l ^ (r & 15)) * 4,                           \
                         &Af[buf][r * 256]);                                 \
        }

    STAGE(bx0, 0);

    #pragma unroll 1
    for (int j = 0; j < 8; ++j) {
        const int bx  = bx0 + j;
        const int cur = j & 1;

        if (j < 7) { STAGE(bx + 1, cur ^ 1); }
        if (j < 7) { asm volatile("s_waitcnt vmcnt(8)" ::: "memory"); }
        else       { asm volatile("s_waitcnt vmcnt(0)" ::: "memory"); }
        __builtin_amdgcn_sched_barrier(0);
        __builtin_amdgcn_s_barrier();          // tile j fully in Af[cur]
        __builtin_amdgcn_sched_barrier(0);

        // ---- GEMM: 8 kk x (4 ds_read-pairs + cvt + 8 MFMA), zero VMEM ----
        floatx4 acc[4][2];
        #pragma unroll
        for (int mi = 0; mi < 4; ++mi)
            #pragma unroll
            for (int ni = 0; ni < 2; ++ni)
                acc[mi][ni] = (floatx4)0.f;

        #pragma unroll
        for (int kk = 0; kk < 8; ++kk) {
            short8 af[4];
            #pragma unroll
            for (int mi = 0; mi < 4; ++mi) {
                const int r  = mi * 16 + l15;
                const int c0 = kk * 8 + lq * 2;
                const int s0 = c0 ^ l15;
                float4 f0 = *(const float4*)&Af[cur][r * 256 + s0 * 4];
                float4 f1 = *(const float4*)&Af[cur][r * 256 + (s0 ^ 1) * 4];
                ushort u[8] = { f2bf(f0.x), f2bf(f0.y), f2bf(f0.z), f2bf(f0.w),
                                f2bf(f1.x), f2bf(f1.y), f2bf(f1.z), f2bf(f1.w) };
                af[mi] = *(short8*)u;
            }
            __builtin_amdgcn_s_setprio(1);
            #pragma unroll
            for (int mi = 0; mi < 4; ++mi)
                #pragma unroll
                for (int ni = 0; ni < 2; ++ni)
                    acc[mi][ni] = __builtin_amdgcn_mfma_f32_16x16x32_bf16(
                        af[mi], bP[kk][ni], acc[mi][ni], 0, 0, 0);
            __builtin_amdgcn_s_setprio(0);
        }

        // ---- epilogue (raw barriers with lgkmcnt-only waits) ----
        float part[4][4];
        #pragma unroll
        for (int mi = 0; mi < 4; ++mi)
            #pragma unroll
            for (int r = 0; r < 4; ++r) part[mi][r] = 0.f;
        #pragma unroll
        for (int ni = 0; ni < 2; ++ni) {
            const float vi = vv[ni];
            const float dp = dd[ni];
            #pragma unroll
            for (int mi = 0; mi < 4; ++mi)
                #pragma unroll
                for (int r = 0; r < 4; ++r)
                    part[mi][r] += vi * fast_tanh(acc[mi][ni][r] + dp);
        }
        #pragma unroll
        for (int mi = 0; mi < 4; ++mi)
            #pragma unroll
            for (int r = 0; r < 4; ++r) {
                float x = part[mi][r];
                x += __shfl_xor(x, 1); x += __shfl_xor(x, 2);
                x += __shfl_xor(x, 4); x += __shfl_xor(x, 8);
                part[mi][r] = x;
            }
        if (l15 == 0) {
            #pragma unroll
            for (int mi = 0; mi < 4; ++mi)
                #pragma unroll
                for (int r = 0; r < 4; ++r)
                    swred[w * 64 + mi * 16 + lq * 4 + r] = part[mi][r];
        }
        asm volatile("s_waitcnt lgkmcnt(0)" ::: "memory");
        __builtin_amdgcn_s_barrier();
        __builtin_amdgcn_sched_barrier(0);

        float s = 0.f;
        #pragma unroll
        for (int ww = 0; ww < 8; ++ww) s += swred[ww * 64 + l];
        const float es = __expf(s);    // |s| <= ~16 -> fp32-safe
        if (w == 0) {
            escore[(size_t)b * Tq + bx * 64 + l] = es;
            float tot = es;
            tot += __shfl_xor(tot, 1);  tot += __shfl_xor(tot, 2);
            tot += __shfl_xor(tot, 4);  tot += __shfl_xor(tot, 8);
            tot += __shfl_xor(tot, 16); tot += __shfl_xor(tot, 32);
            if (l == 0) denomp[bx * Bq + b] = tot;
        }

        // ctx partial from LDS (swizzle-adjusted); wave w covers 8 t-rows
        const int el = l * 4;
        float4 a = {0.f, 0.f, 0.f, 0.f};
        #pragma unroll
        for (int tt = 0; tt < 8; ++tt) {
            const int t  = w * 8 + tt;
            const float pt = __shfl(es, t);
            const int sl = l ^ (t & 15);
            float4 ev = *(const float4*)&Af[cur][t * 256 + sl * 4];
            a.x += pt * ev.x; a.y += pt * ev.y; a.z += pt * ev.z; a.w += pt * ev.w;
        }
        *(float4*)&redf[w * 256 + el] = a;
        asm volatile("s_waitcnt lgkmcnt(0)" ::: "memory");
        __builtin_amdgcn_s_barrier();
        __builtin_amdgcn_sched_barrier(0);
        if (w == 0) {
            float4 o = {0.f, 0.f, 0.f, 0.f};
            #pragma unroll
            for (int ww = 0; ww < 8; ++ww) {
                float4 aw = *(const float4*)&redf[ww * 256 + el];
                o.x += aw.x; o.y += aw.y; o.z += aw.z; o.w += aw.w;
            }
            *(float4*)&ctxp[((size_t)bx * Bq + b) * Eq + el] = o;
        }
        // protect swred/redf (and Af[cur] reads) before next tile reuses them
        asm volatile("s_waitcnt lgkmcnt(0)" ::: "memory");
        __builtin_amdgcn_s_barrier();
        __builtin_amdgcn_sched_barrier(0);
    }
    #undef STAGE
}

// One block per b: denom = sum_c denomp[c][b]; probs *= 1/denom (in place);
// ctx[b][e] = (sum_c ctxp[c][b][e]) / denom.
__global__ __launch_bounds__(256) void finalize_kernel(
    const float* __restrict__ ctxp, const float* __restrict__ denomp,
    float* __restrict__ probs, float* __restrict__ ctx)
{
    const int b   = blockIdx.x;
    const int tid = threadIdx.x;

    float d = denomp[(tid & 31) * Bq + b];
    d += __shfl_xor(d, 1);  d += __shfl_xor(d, 2);  d += __shfl_xor(d, 4);
    d += __shfl_xor(d, 8);  d += __shfl_xor(d, 16);
    const float inv = 1.0f / d;

    float* prow = probs + (size_t)b * Tq + tid * 8;
    float4 p0 = *(const float4*)(prow + 0);
    float4 p1 = *(const float4*)(prow + 4);
    p0.x *= inv; p0.y *= inv; p0.z *= inv; p0.w *= inv;
    p1.x *= inv; p1.y *= inv; p1.z *= inv; p1.w *= inv;
    *(float4*)(prow + 0) = p0;
    *(float4*)(prow + 4) = p1;

    float s = 0.f;
    #pragma unroll 8
    for (int c = 0; c < 32; ++c)
        s += ctxp[((size_t)c * Bq + b) * Eq + tid];
    ctx[b * Eq + tid] = s * inv;
}

extern "C" void kernel_launch(void* const* d_in, const int* in_sizes, int n_in,
                              void* d_out, int out_size, void* d_ws, size_t ws_size,
                              hipStream_t stream) {
    const float* enc = (const float*)d_in[0];  // [64][2048][256]
    const float* dec = (const float*)d_in[1];  // [64][256]
    const float* w1  = (const float*)d_in[2];  // [256][256]
    const float* w2  = (const float*)d_in[3];  // [256][256]
    const float* v   = (const float*)d_in[4];  // [1][256]

    float* out   = (float*)d_out;
    float* ctx   = out;                 // [64][256]  output 0
    float* probs = out + Bq * Eq;       // [64][2048] output 1 (escore first)

    char* ws = (char*)d_ws;
    float*  ctxp   = (float*)ws;                                       // 2 MB
    float*  denomp = (float*)(ws + 2097152);                           // 8 KB
    float*  dproj  = (float*)(ws + 2097152 + 8192);                    // 64 KB
    ushort* w1sw   = (ushort*)(ws + 2097152 + 8192 + 65536);           // 128 KB

    prep_kernel<<<dim3(96), dim3(256), 0, stream>>>(w1, w1sw, dec, w2, dproj);
    scores_ctx_kernel<<<dim3(256), dim3(512), 0, stream>>>(
        enc, w1sw, v, dproj, probs, ctxp, denomp);
    finalize_kernel<<<dim3(Bq), dim3(256), 0, stream>>>(ctxp, denomp, probs, ctx);
}

// Round 10
// 218.262 us; speedup vs baseline: 2.7115x; 1.0624x over previous
//
#include <hip/hip_runtime.h>
#include <hip/hip_bf16.h>
#include <math.h>

#define Bq 64
#define Tq 2048
#define Eq 256
#define Dq 256
#define Iq 256

using short8  = __attribute__((ext_vector_type(8))) short;
using floatx4 = __attribute__((ext_vector_type(4))) float;

// tanh via fast exp + v_rcp approx (error ~1e-6, bf16 GEMM noise dominates)
__device__ __forceinline__ float fast_tanh(float x) {
    float e = __expf(2.0f * x);
    return fmaf(-2.0f, __builtin_amdgcn_rcpf(e + 1.0f), 1.0f);
}

__device__ __forceinline__ ushort f2bf(float x) {
    union { __hip_bfloat16 h; ushort u; } c;
    c.h = __float2bfloat16(x);
    return c.u;
}

// Fused prep:
//  blocks 0..31 : w1 fp32 -> bf16 fragment-ordered: w1sw[kc][i][8], kc=k/8
//  blocks 32..95: dec_proj[b][i] = sum_d dec[b][d]*w2[i][d], b=blockIdx-32
__global__ __launch_bounds__(256) void prep_kernel(
    const float* __restrict__ w1, ushort* __restrict__ w1sw,
    const float* __restrict__ dec, const float* __restrict__ w2,
    float* __restrict__ dproj)
{
    if (blockIdx.x < 32) {
        const int kc = blockIdx.x;
        const int i  = threadIdx.x;
        const float* src = w1 + i * Eq + kc * 8;
        float4 f0 = *(const float4*)src;
        float4 f1 = *(const float4*)(src + 4);
        ushort u[8] = { f2bf(f0.x), f2bf(f0.y), f2bf(f0.z), f2bf(f0.w),
                        f2bf(f1.x), f2bf(f1.y), f2bf(f1.z), f2bf(f1.w) };
        *(short8*)&w1sw[(kc * 256 + i) * 8] = *(short8*)u;
    } else {
        const int b = blockIdx.x - 32;
        const int i = threadIdx.x;
        __shared__ float dls[Dq];
        dls[i] = dec[b * Dq + i];
        __syncthreads();
        const float* w2r = w2 + i * Dq;
        float acc = 0.f;
        #pragma unroll 8
        for (int d = 0; d < Dq; d += 4) {
            float4 wv = *(const float4*)&w2r[d];
            float4 dv = *(const float4*)&dls[d];
            acc += wv.x * dv.x + wv.y * dv.y + wv.z * dv.z + wv.w * dv.w;
        }
        dproj[b * Iq + i] = acc;
    }
}

// Fused scores + unnormalized-context, v8: R1 base (reg-staged bf16 LDS,
// the 224.5us session best) + TRUE depth-2 prefetch:
//  - chunk k+2 float4 loads ISSUE at step k (after B loads: in-order vmcnt
//    means MFMA's B-wait leaves them in flight), cvt+ds_write at step k+1.
//    Load->use distance = one full K-step (>> ~900cy HBM latency).
//  - main-loop barriers are RAW s_barrier + lgkmcnt(0)-only: all LDS writes
//    are ds_write (lgkm domain), A/B loads land in private regs -> no vmcnt
//    drain, so the prefetched chunk SURVIVES the barrier. (global_load_lds
//    variants R5/R6/R9 could never do this: their LDS writes ride vmcnt,
//    forcing full drains -> every "pipeline" was silently depth-0.)
__global__ __launch_bounds__(256, 3) void scores_ctx_kernel(
    const float*  __restrict__ enc,    // [B][T][E] fp32
    const ushort* __restrict__ w1sw,   // fragment-ordered bf16 [32 kc][256 i][8]
    const float*  __restrict__ v,      // [I]
    const float*  __restrict__ dproj,  // [B][I]
    float* __restrict__ escore,        // [B][T] unnormalized exp (probs buffer)
    float* __restrict__ ctxp,          // [32][B][E] context partials
    float* __restrict__ denomp)        // [32][B]
{
    const int b   = blockIdx.y;
    const int bx  = blockIdx.x;
    const int t0  = bx * 64;
    const int tid = threadIdx.x;
    const int w   = tid >> 6;
    const int l   = tid & 63;
    const int l15 = l & 15;
    const int lq  = l >> 4;

    __shared__ alignas(16) ushort As[2][64 * 72];  // 18.4 KB bf16 dbuf, pad 72
    __shared__ float swred[4 * 64];                // 1 KB
    __shared__ float redf[4 * 256];                // 4 KB

    // per-lane v / dproj (wave w only needs i in [w*64, w*64+64))
    float vv[4], dd[4];
    #pragma unroll
    for (int ni = 0; ni < 4; ++ni) {
        const int i = w * 64 + ni * 16 + l15;
        vv[ni] = v[i];
        dd[ni] = dproj[b * Iq + i];
    }

    floatx4 acc[4][4];
    #pragma unroll
    for (int mi = 0; mi < 4; ++mi)
        #pragma unroll
        for (int ni = 0; ni < 4; ++ni)
            acc[mi][ni] = (floatx4)0.f;

    const float* encB = enc + ((size_t)b * Tq + t0) * Eq;
    const int srow = tid >> 4;          // stage row base (+16*r)
    const int sc4  = (tid & 15) * 4;    // stage col (floats)

    // chunk load: 64 rows x 64 k fp32 -> 4 float4 / thread
    #define LOADC(kt, st)                                                     \
        _Pragma("unroll")                                                     \
        for (int r = 0; r < 4; ++r)                                           \
            st[r] = *(const float4*)&encB[(srow + 16 * r) * Eq + (kt) * 64 + sc4];
    // cvt + write one staged chunk into As[buf]
    #define CVTW(st, buf)                                                     \
        _Pragma("unroll")                                                     \
        for (int r = 0; r < 4; ++r) {                                         \
            ushort4 u;                                                        \
            u.x = f2bf(st[r].x); u.y = f2bf(st[r].y);                         \
            u.z = f2bf(st[r].z); u.w = f2bf(st[r].w);                         \
            *(ushort4*)&As[buf][(srow + 16 * r) * 72 + sc4] = u;              \
        }
    // non-draining barrier: LDS writes are lgkm-domain; reg loads survive
    #define BARRIER()                                                         \
        asm volatile("s_waitcnt lgkmcnt(0)" ::: "memory");                    \
        __builtin_amdgcn_s_barrier();                                         \
        __builtin_amdgcn_sched_barrier(0);

    const ushort* vb = w1sw + (w * 64 + l15) * 8 + lq * 2048;

    // one K-step: B loads -> (opt) issue chunk k+2 -> MFMA(cur) -> cvt+write
    // chunk k+1 -> raw barrier
    #define KSTEP(k, cur, LOADNEXT, CVTPREV)                                  \
    {                                                                         \
        short8 bfv[2][4];                                                     \
        _Pragma("unroll")                                                     \
        for (int ks = 0; ks < 2; ++ks)                                        \
            _Pragma("unroll")                                                 \
            for (int ni = 0; ni < 4; ++ni)                                    \
                bfv[ks][ni] = *(const short8*)(vb + ((k) * 8 + ks * 4) * 2048 \
                                               + ni * 128);                   \
        LOADNEXT                                                              \
        _Pragma("unroll")                                                     \
        for (int ks = 0; ks < 2; ++ks) {                                      \
            const int kloc = ks * 32 + lq * 8;                                \
            short8 af[4];                                                     \
            _Pragma("unroll")                                                 \
            for (int mi = 0; mi < 4; ++mi)                                    \
                af[mi] = *(const short8*)&As[cur][(mi * 16 + l15) * 72 + kloc];\
            __builtin_amdgcn_s_setprio(1);                                    \
            _Pragma("unroll")                                                 \
            for (int mi = 0; mi < 4; ++mi)                                    \
                _Pragma("unroll")                                             \
                for (int ni = 0; ni < 4; ++ni)                                \
                    acc[mi][ni] = __builtin_amdgcn_mfma_f32_16x16x32_bf16(    \
                        af[mi], bfv[ks][ni], acc[mi][ni], 0, 0, 0);           \
            __builtin_amdgcn_s_setprio(0);                                    \
        }                                                                     \
        CVTPREV                                                               \
    }

    float4 s0[4], s1[4];
    // prologue: chunk0 + chunk1 loads; chunk0 -> As[0]
    LOADC(0, s0);
    LOADC(1, s1);
    CVTW(s0, 0);
    BARRIER();

    KSTEP(0, 0, LOADC(2, s0);, CVTW(s1, 1); BARRIER();)   // chunk2 in flight
    KSTEP(1, 1, LOADC(3, s1);, CVTW(s0, 0); BARRIER();)   // chunk3 in flight
    KSTEP(2, 0, ;,             CVTW(s1, 1); BARRIER();)
    KSTEP(3, 1, ;,             ;)

    #undef KSTEP
    #undef LOADC
    #undef CVTW

    // epilogue: tanh + v-weight. C layout: col(i)=l15, row(t)=lq*4+reg.
    float part[4][4];
    #pragma unroll
    for (int mi = 0; mi < 4; ++mi)
        #pragma unroll
        for (int r = 0; r < 4; ++r) part[mi][r] = 0.f;

    #pragma unroll
    for (int ni = 0; ni < 4; ++ni) {
        const float vi = vv[ni];
        const float dp = dd[ni];
        #pragma unroll
        for (int mi = 0; mi < 4; ++mi)
            #pragma unroll
            for (int r = 0; r < 4; ++r)
                part[mi][r] += vi * fast_tanh(acc[mi][ni][r] + dp);
    }

    // reduce over i: butterfly within the 16-lane l15 group, then 1 KB LDS.
    #pragma unroll
    for (int mi = 0; mi < 4; ++mi)
        #pragma unroll
        for (int r = 0; r < 4; ++r) {
            float x = part[mi][r];
            x += __shfl_xor(x, 1); x += __shfl_xor(x, 2);
            x += __shfl_xor(x, 4); x += __shfl_xor(x, 8);
            part[mi][r] = x;
        }
    if (l15 == 0) {
        #pragma unroll
        for (int mi = 0; mi < 4; ++mi)
            #pragma unroll
            for (int r = 0; r < 4; ++r)
                swred[w * 64 + mi * 16 + lq * 4 + r] = part[mi][r];
    }
    __syncthreads();

    // every wave redundantly computes all 64 exps (lane l -> t-local l).
    // |s| <= ~16 -> fp32-safe without max-subtraction.
    float s = swred[l] + swred[64 + l] + swred[128 + l] + swred[192 + l];
    const float es = __expf(s);
    if (w == 0) {
        escore[(size_t)b * Tq + t0 + l] = es;
        float tot = es;
        tot += __shfl_xor(tot, 1);  tot += __shfl_xor(tot, 2);
        tot += __shfl_xor(tot, 4);  tot += __shfl_xor(tot, 8);
        tot += __shfl_xor(tot, 16); tot += __shfl_xor(tot, 32);
        if (l == 0) denomp[bx * Bq + b] = tot;
    }

    // fused context partial: ctxp[bx][b][e] = sum_t es[t]*enc[t][e]
    // enc tile is L2-hot (just consumed by the GEMM loads) -> fp32 accuracy.
    const int el = l * 4;               // e in floats
    float4 a = {0.f, 0.f, 0.f, 0.f};
    #pragma unroll 8
    for (int tt = 0; tt < 16; ++tt) {
        const int t = w * 16 + tt;
        const float pt = __shfl(es, t);
        float4 ev = *(const float4*)&encB[t * Eq + el];
        a.x += pt * ev.x; a.y += pt * ev.y; a.z += pt * ev.z; a.w += pt * ev.w;
    }
    *(float4*)&redf[w * 256 + el] = a;
    __syncthreads();
    if (w == 0) {
        float4 a0 = *(const float4*)&redf[0 * 256 + el];
        float4 a1 = *(const float4*)&redf[1 * 256 + el];
        float4 a2 = *(const float4*)&redf[2 * 256 + el];
        float4 a3 = *(const float4*)&redf[3 * 256 + el];
        float4 o;
        o.x = a0.x + a1.x + a2.x + a3.x;
        o.y = a0.y + a1.y + a2.y + a3.y;
        o.z = a0.z + a1.z + a2.z + a3.z;
        o.w = a0.w + a1.w + a2.w + a3.w;
        *(float4*)&ctxp[((size_t)bx * Bq + b) * Eq + el] = o;
    }
}

// One block per b: denom = sum_c denomp[c][b]; probs *= 1/denom (in place);
// ctx[b][e] = (sum_c ctxp[c][b][e]) / denom.
__global__ __launch_bounds__(256) void finalize_kernel(
    const float* __restrict__ ctxp, const float* __restrict__ denomp,
    float* __restrict__ probs, float* __restrict__ ctx)
{
    const int b   = blockIdx.x;
    const int tid = threadIdx.x;

    float d = denomp[(tid & 31) * Bq + b];
    d += __shfl_xor(d, 1);  d += __shfl_xor(d, 2);  d += __shfl_xor(d, 4);
    d += __shfl_xor(d, 8);  d += __shfl_xor(d, 16);
    const float inv = 1.0f / d;

    float* prow = probs + (size_t)b * Tq + tid * 8;
    float4 p0 = *(const float4*)(prow + 0);
    float4 p1 = *(const float4*)(prow + 4);
    p0.x *= inv; p0.y *= inv; p0.z *= inv; p0.w *= inv;
    p1.x *= inv; p1.y *= inv; p1.z *= inv; p1.w *= inv;
    *(float4*)(prow + 0) = p0;
    *(float4*)(prow + 4) = p1;

    float s = 0.f;
    #pragma unroll 8
    for (int c = 0; c < 32; ++c)
        s += ctxp[((size_t)c * Bq + b) * Eq + tid];
    ctx[b * Eq + tid] = s * inv;
}

extern "C" void kernel_launch(void* const* d_in, const int* in_sizes, int n_in,
                              void* d_out, int out_size, void* d_ws, size_t ws_size,
                              hipStream_t stream) {
    const float* enc = (const float*)d_in[0];  // [64][2048][256]
    const float* dec = (const float*)d_in[1];  // [64][256]
    const float* w1  = (const float*)d_in[2];  // [256][256]
    const float* w2  = (const float*)d_in[3];  // [256][256]
    const float* v   = (const float*)d_in[4];  // [1][256]

    float* out   = (float*)d_out;
    float* ctx   = out;                 // [64][256]  output 0
    float* probs = out + Bq * Eq;       // [64][2048] output 1 (escore first)

    char* ws = (char*)d_ws;
    float*  ctxp   = (float*)ws;                        // 2 MB  [32][64][256]
    float*  denomp = (float*)(ws + (32*Bq*Eq)*4);       // 8 KB  [32][64]
    float*  dproj  = (float*)(ws + (32*Bq*Eq)*4 + 32*Bq*4);          // 64 KB
    ushort* w1sw   = (ushort*)(ws + (32*Bq*Eq)*4 + 32*Bq*4 + Bq*Iq*4); // 128 KB

    // all ws buffers are fully overwritten each call -> no memsets needed
    prep_kernel<<<dim3(96), dim3(256), 0, stream>>>(w1, w1sw, dec, w2, dproj);
    scores_ctx_kernel<<<dim3(Tq / 64, Bq), dim3(256), 0, stream>>>(
        enc, w1sw, v, dproj, probs, ctxp, denomp);
    finalize_kernel<<<dim3(Bq), dim3(256), 0, stream>>>(ctxp, denomp, probs, ctx);
}